// Round 9
// baseline (297.318 us; speedup 1.0000x reference)
//
#include <hip/hip_runtime.h>

typedef unsigned short ushort_t;
typedef __attribute__((ext_vector_type(8))) __bf16 bf16x8;
typedef __attribute__((ext_vector_type(4))) float f32x4;

#define MARGIN 1.5e-3f
#define FT 4    // fixup tokens per block

__device__ __forceinline__ float bf2f(ushort_t u){
  union { unsigned int i; float f; } v; v.i = ((unsigned int)u) << 16; return v.f;
}
__device__ __forceinline__ ushort_t f2bf(float f){
  union { float f; unsigned int i; } v; v.f = f;
  unsigned int x = v.i;
  return (ushort_t)((x + 0x7fffu + ((x >> 16) & 1u)) >> 16);
}
// async global->LDS, 16B per lane; LDS dest is wave-uniform base + lane*16
__device__ __forceinline__ void async_load16(const void* g, void* l){
  __builtin_amdgcn_global_load_lds((const __attribute__((address_space(1))) void*)g,
                                   (__attribute__((address_space(3))) void*)l, 16, 0, 0);
}

// ---------------------------------------------------------------------------
// prep: We -> bf16 FRAGMENT-PACKED  WP[e][n>>4][k>>3][n&15][k&7]  (k_expert
// reads B-fragments as one coalesced 1KB wave-load from L2). Wr1 -> bf16
// row-major (r1r2 stages it via global_load_lds). Wr2 -> bf16 hi+lo split.
// fp32 transposes Wr1T/Wr2T for the fp64 fixup kernel.
// ---------------------------------------------------------------------------
__global__ __launch_bounds__(256) void k_prep(const float* __restrict__ We,
    const float* __restrict__ Wr1, const float* __restrict__ Wr2,
    ushort_t* __restrict__ WebP, ushort_t* __restrict__ W1b,
    ushort_t* __restrict__ W2h, ushort_t* __restrict__ W2l,
    float* __restrict__ Wr1T, float* __restrict__ Wr2T)
{
  int idx = blockIdx.x*256 + threadIdx.x;
  if (idx < 1048576){
    int n = (idx >> 8) & 255, k = idx & 255;
    int dst = (idx & ~65535) + ((n>>4)<<12) + ((k>>3)<<7) + ((n&15)<<3) + (k&7);
    WebP[dst] = f2bf(We[idx]);
  }
  if (idx < 65536){
    W1b[idx] = f2bf(Wr1[idx]);
    int k = idx >> 8, o = idx & 255;          // coalesced write, strided read
    Wr1T[idx] = Wr1[o*256 + k];
  }
  if (idx < 4096){
    float w = Wr2[idx];
    ushort_t wh = f2bf(w);
    W2h[idx] = wh;
    W2l[idx] = f2bf(w - bf2f(wh));   // residual, captures next ~8 bits
    int k = idx >> 4, e = idx & 15;
    Wr2T[idx] = Wr2[e*256 + k];
  }
}

// ---------------------------------------------------------------------------
// Fused GEMM1 (bf16 MFMA) + logits MFMA + top2 + softmax + near-tie flagging.
// 64 tokens/block. Proven R7 version: x loads issued BEFORE the async B loads
// so the f2bf conversion's register wait doesn't drain the whole B stream.
// ---------------------------------------------------------------------------
__global__ __launch_bounds__(256) void r1r2_fused(const float* __restrict__ x,
    const ushort_t* __restrict__ W1b, const float* __restrict__ br1,
    const ushort_t* __restrict__ W2h, const ushort_t* __restrict__ W2l,
    const float* __restrict__ br2,
    int* __restrict__ pid, float2* __restrict__ pAB,
    int* __restrict__ fixCnt, int* __restrict__ fixTok)
{
  __shared__ __align__(16) char smem[46336];
  ushort_t* As = (ushort_t*)smem;              // 64 x 72
  char*     Bs = smem + 9216;                  // 256 rows x 128B, XOR-swizzled
  ushort_t* hB = (ushort_t*)smem;              // 64 x 264 (reuse after K-loop)
  float*    lg = (float*)(smem + 41984);       // 64 x 17
  const int tid = threadIdx.x;
  const int wave = tid>>6, lane = tid&63, q = lane>>4, col = lane&15;
  const int tok0 = blockIdx.x*64;

  f32x4 acc[4][4];
  #pragma unroll
  for (int i=0;i<4;i++)
    #pragma unroll
    for (int j=0;j<4;j++) acc[i][j] = f32x4{0.f,0.f,0.f,0.f};

  for (int kc = 0; kc < 4; ++kc){
    const int kb = kc*64;
    __syncthreads();
    // x loads FIRST (their latency overlaps the B async issue + latency)
    f32x4 xv[2][2];
    #pragma unroll
    for (int j=0;j<2;j++){
      int idx = j*256 + tid, row = idx>>3, c8 = idx&7;
      xv[j][0] = *(const f32x4*)&x[(tok0+row)*256 + kb + c8*8];
      xv[j][1] = *(const f32x4*)&x[(tok0+row)*256 + kb + c8*8 + 4];
    }
    // B: 32KB via global_load_lds; wave stages rows [wave*64, wave*64+64)
    #pragma unroll
    for (int i=0;i<8;i++){
      int r0 = wave*64 + i*8;
      int grow = r0 + (lane>>3);
      int kc8 = (lane&7) ^ (grow&7);
      async_load16(W1b + grow*256 + kb + kc8*8, Bs + r0*128);
    }
    // A: convert + write (waits only on x regs; B stream still in flight)
    #pragma unroll
    for (int j=0;j<2;j++){
      int idx = j*256 + tid, row = idx>>3, c8 = idx&7;
      union { uint4 u; ushort_t s[8]; } pk;
      pk.s[0]=f2bf(xv[j][0][0]); pk.s[1]=f2bf(xv[j][0][1]); pk.s[2]=f2bf(xv[j][0][2]); pk.s[3]=f2bf(xv[j][0][3]);
      pk.s[4]=f2bf(xv[j][1][0]); pk.s[5]=f2bf(xv[j][1][1]); pk.s[6]=f2bf(xv[j][1][2]); pk.s[7]=f2bf(xv[j][1][3]);
      *(uint4*)&As[row*72 + c8*8] = pk.u;
    }
    __syncthreads();
    #pragma unroll
    for (int kk=0;kk<2;kk++){
      bf16x8 a[4], b[4];
      #pragma unroll
      for (int rf=0;rf<4;rf++) a[rf] = *(const bf16x8*)&As[(rf*16+col)*72 + kk*32 + q*8];
      #pragma unroll
      for (int cf=0;cf<4;cf++){
        int n = wave*64 + cf*16 + col;
        b[cf] = *(const bf16x8*)(Bs + n*128 + (((kk*4+q) ^ (n&7))*16));
      }
      #pragma unroll
      for (int rf=0;rf<4;rf++)
        #pragma unroll
        for (int cf=0;cf<4;cf++)
          acc[rf][cf] = __builtin_amdgcn_mfma_f32_16x16x32_bf16(a[rf], b[cf], acc[rf][cf], 0,0,0);
    }
  }
  __syncthreads();
  // h = leaky(acc + br1) -> bf16 into hB
  {
    float br1v[4];
    #pragma unroll
    for (int cf=0;cf<4;cf++) br1v[cf] = br1[wave*64 + cf*16 + col];
    #pragma unroll
    for (int rf=0;rf<4;rf++)
      #pragma unroll
      for (int cf=0;cf<4;cf++){
        int o = wave*64 + cf*16 + col;
        #pragma unroll
        for (int r=0;r<4;r++){
          int row = rf*16 + q*4 + r;
          float p = acc[rf][cf][r] + br1v[cf];
          p = p > 0.f ? p : 0.01f*p;
          hB[row*264 + o] = f2bf(p);
        }
      }
  }
  __syncthreads();
  // logits[64x16] = h @ Wr2^T via MFMA; wave handles its 16-token m-tile
  {
    f32x4 acc2 = f32x4{0.f,0.f,0.f,0.f};
    #pragma unroll
    for (int c2=0;c2<8;c2++){
      bf16x8 a2 = *(const bf16x8*)&hB[(wave*16+col)*264 + c2*32 + q*8];
      bf16x8 bh = *(const bf16x8*)&W2h[col*256 + c2*32 + q*8];
      bf16x8 bl = *(const bf16x8*)&W2l[col*256 + c2*32 + q*8];
      acc2 = __builtin_amdgcn_mfma_f32_16x16x32_bf16(a2, bh, acc2, 0,0,0);
      acc2 = __builtin_amdgcn_mfma_f32_16x16x32_bf16(a2, bl, acc2, 0,0,0);
    }
    #pragma unroll
    for (int r=0;r<4;r++) lg[(wave*16 + q*4 + r)*17 + col] = acc2[r];
  }
  __syncthreads();
  if (tid < 64){
    const int tok = tok0 + tid;
    float v[16];
    #pragma unroll
    for (int e=0;e<16;e++) v[e] = lg[tid*17 + e] + br2[e];
    float best=-3.4e38f, sec=-3.4e38f, thr=-3.4e38f; int b1=0, b2=0;
    #pragma unroll
    for (int e=0;e<16;e++){
      float val = v[e];
      if (val > best){ thr=sec; sec=best; b2=b1; best=val; b1=e; }
      else if (val > sec){ thr=sec; sec=val; b2=e; }
      else if (val > thr){ thr=val; }
    }
    float ex = expf(sec - best);
    float s = 1.f + ex;
    float p1 = 1.f/s, p2 = ex/s;
    int eA = b1 < b2 ? b1 : b2;
    int eB = b1 < b2 ? b2 : b1;
    float pA = b1 < b2 ? p1 : p2;
    float pB = b1 < b2 ? p2 : p1;
    pid[tok] = eA*16 + eB;
    pAB[tok] = make_float2(pA, pB);
    if (sec - thr < MARGIN){
      int slot = atomicAdd(fixCnt, 1);
      fixTok[slot] = tok;
    }
  }
}

// ---------------------------------------------------------------------------
// fp64 exact router recompute for near-tie tokens — R12 (kept): FT=4,
// grid 2048, manual wbA/wbB double-buffer with "#pragma unroll 1" outer loop.
// ---------------------------------------------------------------------------
__global__ __launch_bounds__(256) void k_fixup(const float* __restrict__ x,
    const float* __restrict__ Wr1T, const float* __restrict__ br1,
    const float* __restrict__ Wr2T, const float* __restrict__ br2,
    const int* __restrict__ fixCnt, const int* __restrict__ fixTok,
    int* __restrict__ pid, float2* __restrict__ pAB)
{
  __shared__ __align__(16) float xsT[256][FT];   // 4 KB, row k = 16B
  __shared__ double hs[FT*256];                  // 8 KB
  __shared__ double lg4[FT][16][4];              // 2 KB
  const int tid = threadIdx.x;
  const int n = *fixCnt;
  for (int base = blockIdx.x*FT; base < n; base += gridDim.x*FT){
    const int nt = min(FT, n - base);
    __syncthreads();
    // stage x for up to FT tokens, transposed+packed: xsT[c][t]
    for (int i = tid; i < nt*256; i += 256){
      int t = i >> 8, c = i & 255;               // coalesced read per token row
      xsT[c][t] = x[fixTok[base + t]*256 + c];
    }
    __syncthreads();
    // layer 1: thread o computes h[t][o] for all FT tokens; coalesced Wr1T
    // column loads, manual 2-buffer pipeline, outer loop NOT unrolled.
    {
      const int o = tid;
      const float* wp = Wr1T + o;
      double a0=0, a1=0, a2=0, a3=0;
      float wbA[8], wbB[8];
      #pragma unroll
      for (int j=0;j<8;j++) wbA[j] = wp[j*256];
      #pragma unroll 1
      for (int g=0; g<32; g+=2){
        // issue group g+1 loads (in-flight during wbA compute)
        #pragma unroll
        for (int j=0;j<8;j++) wbB[j] = wp[((g+1)*8+j)*256];
        #pragma unroll
        for (int j=0;j<8;j++){
          double w = (double)wbA[j];
          f32x4 xv = *(const f32x4*)&xsT[g*8+j][0];   // 16B broadcast
          a0 += (double)xv[0]*w;
          a1 += (double)xv[1]*w;
          a2 += (double)xv[2]*w;
          a3 += (double)xv[3]*w;
        }
        // issue group g+2 loads (in-flight during wbB compute)
        if (g+2 < 32){
          #pragma unroll
          for (int j=0;j<8;j++) wbA[j] = wp[((g+2)*8+j)*256];
        }
        #pragma unroll
        for (int j=0;j<8;j++){
          double w = (double)wbB[j];
          f32x4 xv = *(const f32x4*)&xsT[(g+1)*8+j][0];
          a0 += (double)xv[0]*w;
          a1 += (double)xv[1]*w;
          a2 += (double)xv[2]*w;
          a3 += (double)xv[3]*w;
        }
      }
      double b = (double)br1[o], v;
      v = a0+b; hs[0*256+o] = v>0.0 ? v : 0.01*v;
      v = a1+b; hs[1*256+o] = v>0.0 ? v : 0.01*v;
      v = a2+b; hs[2*256+o] = v>0.0 ? v : 0.01*v;
      v = a3+b; hs[3*256+o] = v>0.0 ? v : 0.01*v;
    }
    __syncthreads();
    // layer 2: tid = t*64 + e*4 + kq; each thread reduces a 64-k chunk
    {
      const int t = tid>>6, e = (tid>>2)&15, kq = tid&3;
      const double* hp = hs + t*256 + kq*64;
      const float*  w2 = Wr2T + kq*64*16 + e;
      double a0=0, a1=0;
      #pragma unroll 8
      for (int k=0;k<64;k+=2){
        a0 += hp[k]   * (double)w2[k*16];
        a1 += hp[k+1] * (double)w2[(k+1)*16];
      }
      lg4[t][e][kq] = a0 + a1;
    }
    __syncthreads();
    if (tid < FT*16){
      const int t = tid>>4, e = tid&15;
      lg4[t][e][0] = ((lg4[t][e][0]+lg4[t][e][1]) + (lg4[t][e][2]+lg4[t][e][3]))
                     + (double)br2[e];
    }
    __syncthreads();
    if (tid < nt){
      const int tok = fixTok[base + tid];
      double best=-1e300, sec=-1e300; int b1=0, b2=0;
      #pragma unroll
      for (int e=0;e<16;e++){
        double val = lg4[tid][e][0];
        if (val > best){ sec=best; b2=b1; best=val; b1=e; }
        else if (val > sec){ sec=val; b2=e; }
      }
      double ex = exp(sec - best);
      double s = 1.0 + ex;
      double p1 = 1.0/s, p2 = ex/s;
      int eA = b1 < b2 ? b1 : b2;
      int eB = b1 < b2 ? b2 : b1;
      float pA = (float)(b1 < b2 ? p1 : p2);
      float pB = (float)(b1 < b2 ? p2 : p1);
      pid[tok] = eA*16 + eB;
      pAB[tok] = make_float2(pA, pB);
    }
  }
}

__global__ __launch_bounds__(256) void k_hist(const int* __restrict__ pid, int* __restrict__ cnt)
{
  __shared__ int hc[256];
  const int tid = threadIdx.x;
  hc[tid] = 0; __syncthreads();
  atomicAdd(&hc[pid[blockIdx.x*256 + tid]], 1);
  __syncthreads();
  if (hc[tid]) atomicAdd(&cnt[tid], hc[tid]);
}

// tiles are 32 tokens: tc = ceil(c/32). R13: also emit tilePair LUT so
// k_expert does one broadcast load instead of a tid-0 serial binary search
// (8 dependent L2 loads ~1600cy while 255 threads wait).
__global__ __launch_bounds__(256) void k_scan(int* __restrict__ cnt, int* __restrict__ cur,
    int* __restrict__ off, int* __restrict__ tileOff, int* __restrict__ tilePair)
{
  __shared__ int sc[256];
  const int tid = threadIdx.x;
  int c = cnt[tid];
  sc[tid] = c; __syncthreads();
  for (int s=1;s<256;s<<=1){ int v = (tid>=s)? sc[tid-s]:0; __syncthreads(); sc[tid]+=v; __syncthreads(); }
  int inc = sc[tid];
  off[tid] = inc - c;
  cur[tid] = inc - c;
  if (tid==255) off[256] = inc;
  int tc = (c+31)>>5;
  __syncthreads();
  sc[tid] = tc; __syncthreads();
  for (int s=1;s<256;s<<=1){ int v = (tid>=s)? sc[tid-s]:0; __syncthreads(); sc[tid]+=v; __syncthreads(); }
  tileOff[tid] = sc[tid] - tc;
  if (tid==255) tileOff[256] = sc[tid];
  int t0 = sc[tid] - tc;
  for (int i=0;i<tc;i++) tilePair[t0+i] = tid;
}

__global__ __launch_bounds__(256) void k_scatter(const int* __restrict__ pid,
    int* __restrict__ cur, int* __restrict__ sortedTok)
{
  int b = blockIdx.x*256 + threadIdx.x;
  int p = pid[b];
  int slot = atomicAdd(&cur[p], 1);
  sortedTok[slot] = b;
}

// ---------------------------------------------------------------------------
// Expert pair GEMM — R13:
//  * tilePair LUT lookup replaces the tid-0 binary search (+1 barrier gone).
//  * 3-deep rotating register pipeline for B fragments: loads for step s+2
//    issued before step s's MFMAs -> the MFMA waitcnt leaves 16 loads in
//    flight and each group gets ~2 steps to cover L2 latency (R12 evidence:
//    VGPR=72 means the compiler folded the 2-deep buffer flat; 1 step ~80cy
//    of MFMA < ~250cy L2 latency -> exposed).
//  * Everything else = R10 (32-token tiles, dual prob-scaled A, single acc).
// ---------------------------------------------------------------------------
__global__ __launch_bounds__(256) void k_expert(const float* __restrict__ x,
    const ushort_t* __restrict__ WebP, const float* __restrict__ be,
    const int* __restrict__ off, const int* __restrict__ tileOff,
    const int* __restrict__ tilePair,
    const int* __restrict__ sortedTok, const float2* __restrict__ pAB,
    float* __restrict__ out)
{
  const int totTiles = tileOff[256];
  const int bid = blockIdx.x;
  if (bid >= totTiles) return;
  __shared__ __align__(16) char smem[34048];
  ushort_t* xtA = (ushort_t*)smem;            // 32 rows x 512B  [0, 16384)
  ushort_t* xtB = (ushort_t*)(smem + 16384);  // 32 rows x 512B  [16384, 32768)
  __shared__ int toks[32];
  __shared__ float pAs[32], pBs[32];
  const int tid = threadIdx.x;
  const int p = tilePair[bid];                // broadcast load, no search
  const int tstart = off[p] + (bid - tileOff[p])*32;
  const int nt = min(32, off[p+1] - tstart);
  if (tid < 32){
    if (tid < nt){
      int t = sortedTok[tstart + tid];
      toks[tid] = t;
      float2 ab = pAB[t];
      pAs[tid] = ab.x; pBs[tid] = ab.y;
    } else { toks[tid] = -1; pAs[tid]=0.f; pBs[tid]=0.f; }
  }
  __syncthreads();

  // stage dual prob-scaled x-tiles (pad rows: probs=0 -> zeros, never stored)
  #pragma unroll
  for (int j=0;j<4;j++){
    int ci = j*256 + tid, row = ci>>5, c = ci&31;
    int t = toks[row]; t = t < 0 ? 0 : t;
    float pA = pAs[row], pB = pBs[row];
    f32x4 v0 = *(const f32x4*)&x[t*256 + c*8];
    f32x4 v1 = *(const f32x4*)&x[t*256 + c*8 + 4];
    union { uint4 u; ushort_t s[8]; } pk;
    pk.s[0]=f2bf(v0[0]*pA); pk.s[1]=f2bf(v0[1]*pA); pk.s[2]=f2bf(v0[2]*pA); pk.s[3]=f2bf(v0[3]*pA);
    pk.s[4]=f2bf(v1[0]*pA); pk.s[5]=f2bf(v1[1]*pA); pk.s[6]=f2bf(v1[2]*pA); pk.s[7]=f2bf(v1[3]*pA);
    *(uint4*)&xtA[row*256 + ((c ^ (row&7))<<3)] = pk.u;
    pk.s[0]=f2bf(v0[0]*pB); pk.s[1]=f2bf(v0[1]*pB); pk.s[2]=f2bf(v0[2]*pB); pk.s[3]=f2bf(v0[3]*pB);
    pk.s[4]=f2bf(v1[0]*pB); pk.s[5]=f2bf(v1[1]*pB); pk.s[6]=f2bf(v1[2]*pB); pk.s[7]=f2bf(v1[3]*pB);
    *(uint4*)&xtB[row*256 + ((c ^ (row&7))<<3)] = pk.u;
  }
  __syncthreads();

  const int wave = tid>>6, lane = tid&63, q = lane>>4, col = lane&15;
  const int eA = p >> 4, eB = p & 15;

  // acc init = pA*bA + pB*bB per element (row-dependent probs, col-dep bias)
  float pa_r[8], pb_r[8];
  #pragma unroll
  for (int rf=0;rf<2;rf++)
    #pragma unroll
    for (int r=0;r<4;r++){
      int row = rf*16 + q*4 + r;
      pa_r[rf*4+r] = pAs[row]; pb_r[rf*4+r] = pBs[row];
    }
  f32x4 acc[2][4];
  #pragma unroll
  for (int cf=0;cf<4;cf++){
    int o = wave*64 + cf*16 + col;
    float bA_ = be[eA*256 + o], bB_ = be[eB*256 + o];
    #pragma unroll
    for (int rf=0;rf<2;rf++)
      #pragma unroll
      for (int r=0;r<4;r++)
        acc[rf][cf][r] = pa_r[rf*4+r]*bA_ + pb_r[rf*4+r]*bB_;
  }

  // K-loop: no barriers; 3-deep rotating B-fragment pipeline. Step s
  // (s = 0..7): B frag offset = cf*4096 + s*512 ushorts; A k-index 4*s+q.
  const ushort_t* bAp = WebP + eA*65536 + (wave*4)*4096 + q*128 + col*8;
  const ushort_t* bBp = WebP + eB*65536 + (wave*4)*4096 + q*128 + col*8;

  bf16x8 bufA[3][4], bufB[3][4];
  #pragma unroll
  for (int cf=0;cf<4;cf++){
    bufA[0][cf] = *(const bf16x8*)&bAp[cf*4096];
    bufB[0][cf] = *(const bf16x8*)&bBp[cf*4096];
  }
  #pragma unroll
  for (int cf=0;cf<4;cf++){
    bufA[1][cf] = *(const bf16x8*)&bAp[cf*4096 + 512];
    bufB[1][cf] = *(const bf16x8*)&bBp[cf*4096 + 512];
  }
  #pragma unroll
  for (int s=0;s<8;s++){
    const int cb = s % 3;
    // (1) issue step s+2's 8 loads into the rotating slot (2 steps ahead ->
    //     the MFMA waitcnt below leaves 16 loads in flight)
    if (s < 6){
      const int nb = (s+2) % 3;
      #pragma unroll
      for (int cf=0;cf<4;cf++){
        bufA[nb][cf] = *(const bf16x8*)&bAp[cf*4096 + (s+2)*512];
        bufB[nb][cf] = *(const bf16x8*)&bBp[cf*4096 + (s+2)*512];
      }
    }
    // (2) A fragments from LDS (independent counter; overlaps B wait)
    const int k8 = 4*s + q;
    bf16x8 aA[2], aB[2];
    #pragma unroll
    for (int rf=0;rf<2;rf++){
      aA[rf] = *(const bf16x8*)&xtA[(rf*16+col)*256 + ((k8 ^ (col&7))<<3)];
      aB[rf] = *(const bf16x8*)&xtB[(rf*16+col)*256 + ((k8 ^ (col&7))<<3)];
    }
    // (3) 16 MFMAs on the current slot
    #pragma unroll
    for (int cf=0;cf<4;cf++){
      #pragma unroll
      for (int rf=0;rf<2;rf++)
        acc[rf][cf] = __builtin_amdgcn_mfma_f32_16x16x32_bf16(aA[rf], bufA[cb][cf], acc[rf][cf], 0,0,0);
      #pragma unroll
      for (int rf=0;rf<2;rf++)
        acc[rf][cf] = __builtin_amdgcn_mfma_f32_16x16x32_bf16(aB[rf], bufB[cb][cf], acc[rf][cf], 0,0,0);
    }
  }

  // epilogue: out = leaky(acc); single-phase fp32 LDS transpose (32 rows)
  float* obuf = (float*)smem;   // 32 x 264 fp32 = 33792 B (xt dead)
  __syncthreads();
  #pragma unroll
  for (int cf=0;cf<4;cf++){
    int o = wave*64 + cf*16 + col;
    #pragma unroll
    for (int rf=0;rf<2;rf++)
      #pragma unroll
      for (int r=0;r<4;r++){
        int row = rf*16 + q*4 + r;
        float v = acc[rf][cf][r];
        v = v > 0.f ? v : 0.01f*v;
        obuf[row*264 + o] = v;
      }
  }
  __syncthreads();
  #pragma unroll
  for (int j=0;j<8;j++){
    int idx = j*256 + tid;
    int lrow = idx>>6, c4 = idx&63;
    int t = toks[lrow];
    if (t >= 0)
      *(f32x4*)&out[t*256 + c4*4] = *(const f32x4*)&obuf[lrow*264 + c4*4];
  }
}

// ---------------------------------------------------------------------------
extern "C" void kernel_launch(void* const* d_in, const int* in_sizes, int n_in,
                              void* d_out, int out_size, void* d_ws, size_t ws_size,
                              hipStream_t stream)
{
  const float* x   = (const float*)d_in[0];
  const float* Wr1 = (const float*)d_in[1];
  const float* br1 = (const float*)d_in[2];
  const float* Wr2 = (const float*)d_in[3];
  const float* br2 = (const float*)d_in[4];
  const float* We  = (const float*)d_in[5];
  const float* be  = (const float*)d_in[6];
  float* out = (float*)d_out;

  // Workspace layout (non-overlapping, 16B-aligned)
  char* ws = (char*)d_ws;
  ushort_t* WebP     = (ushort_t*)ws;                 // [0,        2097152)
  ushort_t* W1b      = (ushort_t*)(ws + 2097152);     // [2097152,  2228224)
  ushort_t* W2h      = (ushort_t*)(ws + 2228224);     // [2228224,  2236416)
  ushort_t* W2l      = (ushort_t*)(ws + 2236416);     // [2236416,  2244608)
  int*      pid      = (int*)(ws + 2244608);          // [2244608,  2506752)
  float2*   pAB      = (float2*)(ws + 2506752);       // [2506752,  3031040)
  int*      sortedTok= (int*)(ws + 3031040);          // [3031040,  3293184)
  int*      fixTok   = (int*)(ws + 3293184);          // [3293184,  3555328)
  int*      cnt      = (int*)(ws + 3555328);          // 256 ints
  int*      fixCnt   = cnt + 256;                     // 1 int
  int*      cur      = cnt + 272;                     // 256 ints
  int*      off      = cnt + 528;                     // 257 ints
  int*      tileOff  = cnt + 785;                     // 257 ints
  float*    Wr1T     = (float*)(ws + 3559504);        // 256KB fp32 transpose
  float*    Wr2T     = (float*)(ws + 3821648);        // 16KB fp32 transpose
  int*      tilePair = (int*)(ws + 3838032);          // 4096 ints tile->pair LUT

  hipMemsetAsync(cnt, 0, 257*sizeof(int), stream);
  k_prep    <<<4096, 256, 0, stream>>>(We, Wr1, Wr2, WebP, W1b, W2h, W2l, Wr1T, Wr2T);
  r1r2_fused<<<1024, 256, 0, stream>>>(x, W1b, br1, W2h, W2l, br2, pid, pAB, fixCnt, fixTok);
  k_fixup   <<<2048, 256, 0, stream>>>(x, Wr1T, br1, Wr2T, br2, fixCnt, fixTok, pid, pAB);
  k_hist    <<<256,  256, 0, stream>>>(pid, cnt);
  k_scan    <<<1,    256, 0, stream>>>(cnt, cur, off, tileOff, tilePair);
  k_scatter <<<256,  256, 0, stream>>>(pid, cur, sortedTok);
  k_expert  <<<2304, 256, 0, stream>>>(x, WebP, be, off, tileOff, tilePair, sortedTok, pAB, out);
}

// Round 10
// 242.053 us; speedup vs baseline: 1.2283x; 1.2283x over previous
//
#include <hip/hip_runtime.h>

typedef unsigned short ushort_t;
typedef __attribute__((ext_vector_type(8))) __bf16 bf16x8;
typedef __attribute__((ext_vector_type(4))) float f32x4;

#define MARGIN 1.5e-3f
#define FT 4    // fixup tokens per block

__device__ __forceinline__ float bf2f(ushort_t u){
  union { unsigned int i; float f; } v; v.i = ((unsigned int)u) << 16; return v.f;
}
__device__ __forceinline__ ushort_t f2bf(float f){
  union { float f; unsigned int i; } v; v.f = f;
  unsigned int x = v.i;
  return (ushort_t)((x + 0x7fffu + ((x >> 16) & 1u)) >> 16);
}
// async global->LDS, 16B per lane; LDS dest is wave-uniform base + lane*16
__device__ __forceinline__ void async_load16(const void* g, void* l){
  __builtin_amdgcn_global_load_lds((const __attribute__((address_space(1))) void*)g,
                                   (__attribute__((address_space(3))) void*)l, 16, 0, 0);
}

// ---------------------------------------------------------------------------
// prep: We -> bf16 FRAGMENT-PACKED  WP[e][n>>4][k>>3][n&15][k&7]  (k_expert
// reads B-fragments as one coalesced 1KB wave-load from L2). Wr1 -> bf16
// row-major (r1r2 stages it via global_load_lds). Wr2 -> bf16 hi+lo split.
// fp32 transposes Wr1T/Wr2T for the fp64 fixup kernel.
// ---------------------------------------------------------------------------
__global__ __launch_bounds__(256) void k_prep(const float* __restrict__ We,
    const float* __restrict__ Wr1, const float* __restrict__ Wr2,
    ushort_t* __restrict__ WebP, ushort_t* __restrict__ W1b,
    ushort_t* __restrict__ W2h, ushort_t* __restrict__ W2l,
    float* __restrict__ Wr1T, float* __restrict__ Wr2T)
{
  int idx = blockIdx.x*256 + threadIdx.x;
  if (idx < 1048576){
    int n = (idx >> 8) & 255, k = idx & 255;
    int dst = (idx & ~65535) + ((n>>4)<<12) + ((k>>3)<<7) + ((n&15)<<3) + (k&7);
    WebP[dst] = f2bf(We[idx]);
  }
  if (idx < 65536){
    W1b[idx] = f2bf(Wr1[idx]);
    int k = idx >> 8, o = idx & 255;          // coalesced write, strided read
    Wr1T[idx] = Wr1[o*256 + k];
  }
  if (idx < 4096){
    float w = Wr2[idx];
    ushort_t wh = f2bf(w);
    W2h[idx] = wh;
    W2l[idx] = f2bf(w - bf2f(wh));   // residual, captures next ~8 bits
    int k = idx >> 4, e = idx & 15;
    Wr2T[idx] = Wr2[e*256 + k];
  }
}

// ---------------------------------------------------------------------------
// Fused GEMM1 (bf16 MFMA) + logits MFMA + top2 + softmax + near-tie flagging.
// 64 tokens/block. Proven R7 version: x loads issued BEFORE the async B loads
// so the f2bf conversion's register wait doesn't drain the whole B stream.
// ---------------------------------------------------------------------------
__global__ __launch_bounds__(256) void r1r2_fused(const float* __restrict__ x,
    const ushort_t* __restrict__ W1b, const float* __restrict__ br1,
    const ushort_t* __restrict__ W2h, const ushort_t* __restrict__ W2l,
    const float* __restrict__ br2,
    int* __restrict__ pid, float2* __restrict__ pAB,
    int* __restrict__ fixCnt, int* __restrict__ fixTok)
{
  __shared__ __align__(16) char smem[46336];
  ushort_t* As = (ushort_t*)smem;              // 64 x 72
  char*     Bs = smem + 9216;                  // 256 rows x 128B, XOR-swizzled
  ushort_t* hB = (ushort_t*)smem;              // 64 x 264 (reuse after K-loop)
  float*    lg = (float*)(smem + 41984);       // 64 x 17
  const int tid = threadIdx.x;
  const int wave = tid>>6, lane = tid&63, q = lane>>4, col = lane&15;
  const int tok0 = blockIdx.x*64;

  f32x4 acc[4][4];
  #pragma unroll
  for (int i=0;i<4;i++)
    #pragma unroll
    for (int j=0;j<4;j++) acc[i][j] = f32x4{0.f,0.f,0.f,0.f};

  for (int kc = 0; kc < 4; ++kc){
    const int kb = kc*64;
    __syncthreads();
    // x loads FIRST (their latency overlaps the B async issue + latency)
    f32x4 xv[2][2];
    #pragma unroll
    for (int j=0;j<2;j++){
      int idx = j*256 + tid, row = idx>>3, c8 = idx&7;
      xv[j][0] = *(const f32x4*)&x[(tok0+row)*256 + kb + c8*8];
      xv[j][1] = *(const f32x4*)&x[(tok0+row)*256 + kb + c8*8 + 4];
    }
    // B: 32KB via global_load_lds; wave stages rows [wave*64, wave*64+64)
    #pragma unroll
    for (int i=0;i<8;i++){
      int r0 = wave*64 + i*8;
      int grow = r0 + (lane>>3);
      int kc8 = (lane&7) ^ (grow&7);
      async_load16(W1b + grow*256 + kb + kc8*8, Bs + r0*128);
    }
    // A: convert + write (waits only on x regs; B stream still in flight)
    #pragma unroll
    for (int j=0;j<2;j++){
      int idx = j*256 + tid, row = idx>>3, c8 = idx&7;
      union { uint4 u; ushort_t s[8]; } pk;
      pk.s[0]=f2bf(xv[j][0][0]); pk.s[1]=f2bf(xv[j][0][1]); pk.s[2]=f2bf(xv[j][0][2]); pk.s[3]=f2bf(xv[j][0][3]);
      pk.s[4]=f2bf(xv[j][1][0]); pk.s[5]=f2bf(xv[j][1][1]); pk.s[6]=f2bf(xv[j][1][2]); pk.s[7]=f2bf(xv[j][1][3]);
      *(uint4*)&As[row*72 + c8*8] = pk.u;
    }
    __syncthreads();
    #pragma unroll
    for (int kk=0;kk<2;kk++){
      bf16x8 a[4], b[4];
      #pragma unroll
      for (int rf=0;rf<4;rf++) a[rf] = *(const bf16x8*)&As[(rf*16+col)*72 + kk*32 + q*8];
      #pragma unroll
      for (int cf=0;cf<4;cf++){
        int n = wave*64 + cf*16 + col;
        b[cf] = *(const bf16x8*)(Bs + n*128 + (((kk*4+q) ^ (n&7))*16));
      }
      #pragma unroll
      for (int rf=0;rf<4;rf++)
        #pragma unroll
        for (int cf=0;cf<4;cf++)
          acc[rf][cf] = __builtin_amdgcn_mfma_f32_16x16x32_bf16(a[rf], b[cf], acc[rf][cf], 0,0,0);
    }
  }
  __syncthreads();
  // h = leaky(acc + br1) -> bf16 into hB
  {
    float br1v[4];
    #pragma unroll
    for (int cf=0;cf<4;cf++) br1v[cf] = br1[wave*64 + cf*16 + col];
    #pragma unroll
    for (int rf=0;rf<4;rf++)
      #pragma unroll
      for (int cf=0;cf<4;cf++){
        int o = wave*64 + cf*16 + col;
        #pragma unroll
        for (int r=0;r<4;r++){
          int row = rf*16 + q*4 + r;
          float p = acc[rf][cf][r] + br1v[cf];
          p = p > 0.f ? p : 0.01f*p;
          hB[row*264 + o] = f2bf(p);
        }
      }
  }
  __syncthreads();
  // logits[64x16] = h @ Wr2^T via MFMA; wave handles its 16-token m-tile
  {
    f32x4 acc2 = f32x4{0.f,0.f,0.f,0.f};
    #pragma unroll
    for (int c2=0;c2<8;c2++){
      bf16x8 a2 = *(const bf16x8*)&hB[(wave*16+col)*264 + c2*32 + q*8];
      bf16x8 bh = *(const bf16x8*)&W2h[col*256 + c2*32 + q*8];
      bf16x8 bl = *(const bf16x8*)&W2l[col*256 + c2*32 + q*8];
      acc2 = __builtin_amdgcn_mfma_f32_16x16x32_bf16(a2, bh, acc2, 0,0,0);
      acc2 = __builtin_amdgcn_mfma_f32_16x16x32_bf16(a2, bl, acc2, 0,0,0);
    }
    #pragma unroll
    for (int r=0;r<4;r++) lg[(wave*16 + q*4 + r)*17 + col] = acc2[r];
  }
  __syncthreads();
  if (tid < 64){
    const int tok = tok0 + tid;
    float v[16];
    #pragma unroll
    for (int e=0;e<16;e++) v[e] = lg[tid*17 + e] + br2[e];
    float best=-3.4e38f, sec=-3.4e38f, thr=-3.4e38f; int b1=0, b2=0;
    #pragma unroll
    for (int e=0;e<16;e++){
      float val = v[e];
      if (val > best){ thr=sec; sec=best; b2=b1; best=val; b1=e; }
      else if (val > sec){ thr=sec; sec=val; b2=e; }
      else if (val > thr){ thr=val; }
    }
    float ex = expf(sec - best);
    float s = 1.f + ex;
    float p1 = 1.f/s, p2 = ex/s;
    int eA = b1 < b2 ? b1 : b2;
    int eB = b1 < b2 ? b2 : b1;
    float pA = b1 < b2 ? p1 : p2;
    float pB = b1 < b2 ? p2 : p1;
    pid[tok] = eA*16 + eB;
    pAB[tok] = make_float2(pA, pB);
    if (sec - thr < MARGIN){
      int slot = atomicAdd(fixCnt, 1);
      fixTok[slot] = tok;
    }
  }
}

// ---------------------------------------------------------------------------
// fp64 exact router recompute for near-tie tokens — R12 (kept): FT=4,
// grid 2048, manual wbA/wbB double-buffer with "#pragma unroll 1" outer loop.
// ---------------------------------------------------------------------------
__global__ __launch_bounds__(256) void k_fixup(const float* __restrict__ x,
    const float* __restrict__ Wr1T, const float* __restrict__ br1,
    const float* __restrict__ Wr2T, const float* __restrict__ br2,
    const int* __restrict__ fixCnt, const int* __restrict__ fixTok,
    int* __restrict__ pid, float2* __restrict__ pAB)
{
  __shared__ __align__(16) float xsT[256][FT];   // 4 KB, row k = 16B
  __shared__ double hs[FT*256];                  // 8 KB
  __shared__ double lg4[FT][16][4];              // 2 KB
  const int tid = threadIdx.x;
  const int n = *fixCnt;
  for (int base = blockIdx.x*FT; base < n; base += gridDim.x*FT){
    const int nt = min(FT, n - base);
    __syncthreads();
    // stage x for up to FT tokens, transposed+packed: xsT[c][t]
    for (int i = tid; i < nt*256; i += 256){
      int t = i >> 8, c = i & 255;               // coalesced read per token row
      xsT[c][t] = x[fixTok[base + t]*256 + c];
    }
    __syncthreads();
    // layer 1: thread o computes h[t][o] for all FT tokens; coalesced Wr1T
    // column loads, manual 2-buffer pipeline, outer loop NOT unrolled.
    {
      const int o = tid;
      const float* wp = Wr1T + o;
      double a0=0, a1=0, a2=0, a3=0;
      float wbA[8], wbB[8];
      #pragma unroll
      for (int j=0;j<8;j++) wbA[j] = wp[j*256];
      #pragma unroll 1
      for (int g=0; g<32; g+=2){
        // issue group g+1 loads (in-flight during wbA compute)
        #pragma unroll
        for (int j=0;j<8;j++) wbB[j] = wp[((g+1)*8+j)*256];
        #pragma unroll
        for (int j=0;j<8;j++){
          double w = (double)wbA[j];
          f32x4 xv = *(const f32x4*)&xsT[g*8+j][0];   // 16B broadcast
          a0 += (double)xv[0]*w;
          a1 += (double)xv[1]*w;
          a2 += (double)xv[2]*w;
          a3 += (double)xv[3]*w;
        }
        // issue group g+2 loads (in-flight during wbB compute)
        if (g+2 < 32){
          #pragma unroll
          for (int j=0;j<8;j++) wbA[j] = wp[((g+2)*8+j)*256];
        }
        #pragma unroll
        for (int j=0;j<8;j++){
          double w = (double)wbB[j];
          f32x4 xv = *(const f32x4*)&xsT[(g+1)*8+j][0];
          a0 += (double)xv[0]*w;
          a1 += (double)xv[1]*w;
          a2 += (double)xv[2]*w;
          a3 += (double)xv[3]*w;
        }
      }
      double b = (double)br1[o], v;
      v = a0+b; hs[0*256+o] = v>0.0 ? v : 0.01*v;
      v = a1+b; hs[1*256+o] = v>0.0 ? v : 0.01*v;
      v = a2+b; hs[2*256+o] = v>0.0 ? v : 0.01*v;
      v = a3+b; hs[3*256+o] = v>0.0 ? v : 0.01*v;
    }
    __syncthreads();
    // layer 2: tid = t*64 + e*4 + kq; each thread reduces a 64-k chunk
    {
      const int t = tid>>6, e = (tid>>2)&15, kq = tid&3;
      const double* hp = hs + t*256 + kq*64;
      const float*  w2 = Wr2T + kq*64*16 + e;
      double a0=0, a1=0;
      #pragma unroll 8
      for (int k=0;k<64;k+=2){
        a0 += hp[k]   * (double)w2[k*16];
        a1 += hp[k+1] * (double)w2[(k+1)*16];
      }
      lg4[t][e][kq] = a0 + a1;
    }
    __syncthreads();
    if (tid < FT*16){
      const int t = tid>>4, e = tid&15;
      lg4[t][e][0] = ((lg4[t][e][0]+lg4[t][e][1]) + (lg4[t][e][2]+lg4[t][e][3]))
                     + (double)br2[e];
    }
    __syncthreads();
    if (tid < nt){
      const int tok = fixTok[base + tid];
      double best=-1e300, sec=-1e300; int b1=0, b2=0;
      #pragma unroll
      for (int e=0;e<16;e++){
        double val = lg4[tid][e][0];
        if (val > best){ sec=best; b2=b1; best=val; b1=e; }
        else if (val > sec){ sec=val; b2=e; }
      }
      double ex = exp(sec - best);
      double s = 1.0 + ex;
      double p1 = 1.0/s, p2 = ex/s;
      int eA = b1 < b2 ? b1 : b2;
      int eB = b1 < b2 ? b2 : b1;
      float pA = (float)(b1 < b2 ? p1 : p2);
      float pB = (float)(b1 < b2 ? p2 : p1);
      pid[tok] = eA*16 + eB;
      pAB[tok] = make_float2(pA, pB);
    }
  }
}

// ---------------------------------------------------------------------------
// R14 sort chain: NO global atomics anywhere.
// k_hist: LDS histogram -> blockHistT[p][b] (transposed: colscan reads coalesced)
// ---------------------------------------------------------------------------
__global__ __launch_bounds__(256) void k_hist(const int* __restrict__ pid,
    int* __restrict__ blockHistT)
{
  __shared__ int hc[256];
  const int tid = threadIdx.x;
  hc[tid] = 0; __syncthreads();
  atomicAdd(&hc[pid[blockIdx.x*256 + tid]], 1);   // LDS atomic only
  __syncthreads();
  blockHistT[tid*256 + blockIdx.x] = hc[tid];     // scattered 4B store, hidden
}

// one block per pair p: scan its per-block counts over the 256 hist blocks.
// outputs blockPre[b][p] (exclusive prefix, ROW-major: k_scatter reads its
// 1KB row from L1) and cnt[p] (total) — replaces all global atomics.
__global__ __launch_bounds__(256) void k_colscan(const int* __restrict__ blockHistT,
    int* __restrict__ blockPre, int* __restrict__ cnt)
{
  __shared__ int sc[256];
  const int p = blockIdx.x, b = threadIdx.x;
  int v = blockHistT[p*256 + b];                  // coalesced 1KB row
  sc[b] = v; __syncthreads();
  for (int s=1;s<256;s<<=1){ int u = (b>=s)? sc[b-s]:0; __syncthreads(); sc[b]+=u; __syncthreads(); }
  blockPre[b*256 + p] = sc[b] - v;                // scattered store, hidden
  if (b == 255) cnt[p] = sc[255];
}

// tiles are 32 tokens: tc = ceil(c/32). Emits off, tileOff, tilePair LUT.
__global__ __launch_bounds__(256) void k_scan(const int* __restrict__ cnt,
    int* __restrict__ off, int* __restrict__ tileOff, int* __restrict__ tilePair)
{
  __shared__ int sc[256];
  const int tid = threadIdx.x;
  int c = cnt[tid];
  sc[tid] = c; __syncthreads();
  for (int s=1;s<256;s<<=1){ int v = (tid>=s)? sc[tid-s]:0; __syncthreads(); sc[tid]+=v; __syncthreads(); }
  int inc = sc[tid];
  off[tid] = inc - c;
  if (tid==255) off[256] = inc;
  int tc = (c+31)>>5;
  __syncthreads();
  sc[tid] = tc; __syncthreads();
  for (int s=1;s<256;s<<=1){ int v = (tid>=s)? sc[tid-s]:0; __syncthreads(); sc[tid]+=v; __syncthreads(); }
  tileOff[tid] = sc[tid] - tc;
  if (tid==255) tileOff[256] = sc[tid];
  int t0 = sc[tid] - tc;
  for (int i=0;i<tc;i++) tilePair[t0+i] = tid;
}

// deterministic scatter: LDS atomic gives the within-block rank; global slot
// = off[p] + blockPre[b][p] + rank. Zero global atomics, each slot written once.
__global__ __launch_bounds__(256) void k_scatter(const int* __restrict__ pid,
    const int* __restrict__ off, const int* __restrict__ blockPre,
    int* __restrict__ sortedTok)
{
  __shared__ int lc[256];
  const int tid = threadIdx.x, b = blockIdx.x;
  lc[tid] = 0; __syncthreads();
  int tok = b*256 + tid;
  int p = pid[tok];
  int local = atomicAdd(&lc[p], 1);               // LDS atomic only
  sortedTok[off[p] + blockPre[b*256 + p] + local] = tok;
}

// ---------------------------------------------------------------------------
// Expert pair GEMM — R13 (kept): tilePair LUT, 3-deep rotating B pipeline,
// 32-token tiles, dual prob-scaled A, single acc.
// ---------------------------------------------------------------------------
__global__ __launch_bounds__(256) void k_expert(const float* __restrict__ x,
    const ushort_t* __restrict__ WebP, const float* __restrict__ be,
    const int* __restrict__ off, const int* __restrict__ tileOff,
    const int* __restrict__ tilePair,
    const int* __restrict__ sortedTok, const float2* __restrict__ pAB,
    float* __restrict__ out)
{
  const int totTiles = tileOff[256];
  const int bid = blockIdx.x;
  if (bid >= totTiles) return;
  __shared__ __align__(16) char smem[34048];
  ushort_t* xtA = (ushort_t*)smem;            // 32 rows x 512B  [0, 16384)
  ushort_t* xtB = (ushort_t*)(smem + 16384);  // 32 rows x 512B  [16384, 32768)
  __shared__ int toks[32];
  __shared__ float pAs[32], pBs[32];
  const int tid = threadIdx.x;
  const int p = tilePair[bid];                // broadcast load, no search
  const int tstart = off[p] + (bid - tileOff[p])*32;
  const int nt = min(32, off[p+1] - tstart);
  if (tid < 32){
    if (tid < nt){
      int t = sortedTok[tstart + tid];
      toks[tid] = t;
      float2 ab = pAB[t];
      pAs[tid] = ab.x; pBs[tid] = ab.y;
    } else { toks[tid] = -1; pAs[tid]=0.f; pBs[tid]=0.f; }
  }
  __syncthreads();

  // stage dual prob-scaled x-tiles (pad rows: probs=0 -> zeros, never stored)
  #pragma unroll
  for (int j=0;j<4;j++){
    int ci = j*256 + tid, row = ci>>5, c = ci&31;
    int t = toks[row]; t = t < 0 ? 0 : t;
    float pA = pAs[row], pB = pBs[row];
    f32x4 v0 = *(const f32x4*)&x[t*256 + c*8];
    f32x4 v1 = *(const f32x4*)&x[t*256 + c*8 + 4];
    union { uint4 u; ushort_t s[8]; } pk;
    pk.s[0]=f2bf(v0[0]*pA); pk.s[1]=f2bf(v0[1]*pA); pk.s[2]=f2bf(v0[2]*pA); pk.s[3]=f2bf(v0[3]*pA);
    pk.s[4]=f2bf(v1[0]*pA); pk.s[5]=f2bf(v1[1]*pA); pk.s[6]=f2bf(v1[2]*pA); pk.s[7]=f2bf(v1[3]*pA);
    *(uint4*)&xtA[row*256 + ((c ^ (row&7))<<3)] = pk.u;
    pk.s[0]=f2bf(v0[0]*pB); pk.s[1]=f2bf(v0[1]*pB); pk.s[2]=f2bf(v0[2]*pB); pk.s[3]=f2bf(v0[3]*pB);
    pk.s[4]=f2bf(v1[0]*pB); pk.s[5]=f2bf(v1[1]*pB); pk.s[6]=f2bf(v1[2]*pB); pk.s[7]=f2bf(v1[3]*pB);
    *(uint4*)&xtB[row*256 + ((c ^ (row&7))<<3)] = pk.u;
  }
  __syncthreads();

  const int wave = tid>>6, lane = tid&63, q = lane>>4, col = lane&15;
  const int eA = p >> 4, eB = p & 15;

  // acc init = pA*bA + pB*bB per element (row-dependent probs, col-dep bias)
  float pa_r[8], pb_r[8];
  #pragma unroll
  for (int rf=0;rf<2;rf++)
    #pragma unroll
    for (int r=0;r<4;r++){
      int row = rf*16 + q*4 + r;
      pa_r[rf*4+r] = pAs[row]; pb_r[rf*4+r] = pBs[row];
    }
  f32x4 acc[2][4];
  #pragma unroll
  for (int cf=0;cf<4;cf++){
    int o = wave*64 + cf*16 + col;
    float bA_ = be[eA*256 + o], bB_ = be[eB*256 + o];
    #pragma unroll
    for (int rf=0;rf<2;rf++)
      #pragma unroll
      for (int r=0;r<4;r++)
        acc[rf][cf][r] = pa_r[rf*4+r]*bA_ + pb_r[rf*4+r]*bB_;
  }

  // K-loop: no barriers; 3-deep rotating B-fragment pipeline. Step s
  // (s = 0..7): B frag offset = cf*4096 + s*512 ushorts; A k-index 4*s+q.
  const ushort_t* bAp = WebP + eA*65536 + (wave*4)*4096 + q*128 + col*8;
  const ushort_t* bBp = WebP + eB*65536 + (wave*4)*4096 + q*128 + col*8;

  bf16x8 bufA[3][4], bufB[3][4];
  #pragma unroll
  for (int cf=0;cf<4;cf++){
    bufA[0][cf] = *(const bf16x8*)&bAp[cf*4096];
    bufB[0][cf] = *(const bf16x8*)&bBp[cf*4096];
  }
  #pragma unroll
  for (int cf=0;cf<4;cf++){
    bufA[1][cf] = *(const bf16x8*)&bAp[cf*4096 + 512];
    bufB[1][cf] = *(const bf16x8*)&bBp[cf*4096 + 512];
  }
  #pragma unroll
  for (int s=0;s<8;s++){
    const int cb = s % 3;
    // (1) issue step s+2's 8 loads into the rotating slot (2 steps ahead ->
    //     the MFMA waitcnt below leaves 16 loads in flight)
    if (s < 6){
      const int nb = (s+2) % 3;
      #pragma unroll
      for (int cf=0;cf<4;cf++){
        bufA[nb][cf] = *(const bf16x8*)&bAp[cf*4096 + (s+2)*512];
        bufB[nb][cf] = *(const bf16x8*)&bBp[cf*4096 + (s+2)*512];
      }
    }
    // (2) A fragments from LDS (independent counter; overlaps B wait)
    const int k8 = 4*s + q;
    bf16x8 aA[2], aB[2];
    #pragma unroll
    for (int rf=0;rf<2;rf++){
      aA[rf] = *(const bf16x8*)&xtA[(rf*16+col)*256 + ((k8 ^ (col&7))<<3)];
      aB[rf] = *(const bf16x8*)&xtB[(rf*16+col)*256 + ((k8 ^ (col&7))<<3)];
    }
    // (3) 16 MFMAs on the current slot
    #pragma unroll
    for (int cf=0;cf<4;cf++){
      #pragma unroll
      for (int rf=0;rf<2;rf++)
        acc[rf][cf] = __builtin_amdgcn_mfma_f32_16x16x32_bf16(aA[rf], bufA[cb][cf], acc[rf][cf], 0,0,0);
      #pragma unroll
      for (int rf=0;rf<2;rf++)
        acc[rf][cf] = __builtin_amdgcn_mfma_f32_16x16x32_bf16(aB[rf], bufB[cb][cf], acc[rf][cf], 0,0,0);
    }
  }

  // epilogue: out = leaky(acc); single-phase fp32 LDS transpose (32 rows)
  float* obuf = (float*)smem;   // 32 x 264 fp32 = 33792 B (xt dead)
  __syncthreads();
  #pragma unroll
  for (int cf=0;cf<4;cf++){
    int o = wave*64 + cf*16 + col;
    #pragma unroll
    for (int rf=0;rf<2;rf++)
      #pragma unroll
      for (int r=0;r<4;r++){
        int row = rf*16 + q*4 + r;
        float v = acc[rf][cf][r];
        v = v > 0.f ? v : 0.01f*v;
        obuf[row*264 + o] = v;
      }
  }
  __syncthreads();
  #pragma unroll
  for (int j=0;j<8;j++){
    int idx = j*256 + tid;
    int lrow = idx>>6, c4 = idx&63;
    int t = toks[lrow];
    if (t >= 0)
      *(f32x4*)&out[t*256 + c4*4] = *(const f32x4*)&obuf[lrow*264 + c4*4];
  }
}

// ---------------------------------------------------------------------------
extern "C" void kernel_launch(void* const* d_in, const int* in_sizes, int n_in,
                              void* d_out, int out_size, void* d_ws, size_t ws_size,
                              hipStream_t stream)
{
  const float* x   = (const float*)d_in[0];
  const float* Wr1 = (const float*)d_in[1];
  const float* br1 = (const float*)d_in[2];
  const float* Wr2 = (const float*)d_in[3];
  const float* br2 = (const float*)d_in[4];
  const float* We  = (const float*)d_in[5];
  const float* be  = (const float*)d_in[6];
  float* out = (float*)d_out;

  // Workspace layout (non-overlapping, 16B-aligned)
  char* ws = (char*)d_ws;
  ushort_t* WebP     = (ushort_t*)ws;                 // [0,        2097152)
  ushort_t* W1b      = (ushort_t*)(ws + 2097152);     // [2097152,  2228224)
  ushort_t* W2h      = (ushort_t*)(ws + 2228224);     // [2228224,  2236416)
  ushort_t* W2l      = (ushort_t*)(ws + 2236416);     // [2236416,  2244608)
  int*      pid      = (int*)(ws + 2244608);          // [2244608,  2506752)
  float2*   pAB      = (float2*)(ws + 2506752);       // [2506752,  3031040)
  int*      sortedTok= (int*)(ws + 3031040);          // [3031040,  3293184)
  int*      fixTok   = (int*)(ws + 3293184);          // [3293184,  3555328)
  int*      cnt      = (int*)(ws + 3555328);          // 256 ints
  int*      fixCnt   = cnt + 256;                     // 1 int
  int*      off      = cnt + 528;                     // 257 ints
  int*      tileOff  = cnt + 785;                     // 257 ints
  float*    Wr1T     = (float*)(ws + 3559504);        // 256KB fp32 transpose
  float*    Wr2T     = (float*)(ws + 3821648);        // 16KB fp32 transpose
  int*      tilePair = (int*)(ws + 3838032);          // 4096 ints tile->pair LUT
  int*      blockHistT=(int*)(ws + 3854416);          // 256x256 ints [p][b]
  int*      blockPre = (int*)(ws + 4116560);          // 256x256 ints [b][p]

  hipMemsetAsync(fixCnt, 0, sizeof(int), stream);
  k_prep    <<<4096, 256, 0, stream>>>(We, Wr1, Wr2, WebP, W1b, W2h, W2l, Wr1T, Wr2T);
  r1r2_fused<<<1024, 256, 0, stream>>>(x, W1b, br1, W2h, W2l, br2, pid, pAB, fixCnt, fixTok);
  k_fixup   <<<2048, 256, 0, stream>>>(x, Wr1T, br1, Wr2T, br2, fixCnt, fixTok, pid, pAB);
  k_hist    <<<256,  256, 0, stream>>>(pid, blockHistT);
  k_colscan <<<256,  256, 0, stream>>>(blockHistT, blockPre, cnt);
  k_scan    <<<1,    256, 0, stream>>>(cnt, off, tileOff, tilePair);
  k_scatter <<<256,  256, 0, stream>>>(pid, off, blockPre, sortedTok);
  k_expert  <<<2304, 256, 0, stream>>>(x, WebP, be, off, tileOff, tilePair, sortedTok, pAB, out);
}